// Round 10
// baseline (227.942 us; speedup 1.0000x reference)
//
#include <hip/hip_runtime.h>

// Problem constants (from setup_inputs): B=4, N=100000, M=64
#define B_IMGS 4
#define N_PROP 100000
#define M_GT   64

// Output layout (flat f32): decoded[B*N*4] | targets[B*N*4] | matches[B*N]
//
// R10: 3-dispatch discrimination experiment (see commit message):
//   A = roihead_full<1>  — R9 anchor, REP=1
//   C = roihead_split<4> — m-split occupancy probe (12512 waves, 32 gts/wave)
//   B = roihead_full<3>  — surfaces packed-key loop counters in top-5
// Order A,C,B: B (bit-identical math to A) writes last -> round passes even
// if C is wrong. C's own correctness is validated only if promoted solo.

// ---------- shared epilogue (exact fallback + encode + decode) ----------
__device__ __forceinline__ void finish_and_store(
    const float4 p, const float4 d, const float4* __restrict__ gt4,
    const float* __restrict__ ga_s, float ap, unsigned k1, unsigned k2,
    float* __restrict__ pout, long pi)
{
    int bi = 63 - (int)(k1 & 63u);
    const float f1 = __uint_as_float(k1 & 0xFFFFFFC0u);
    const float f2 = __uint_as_float(k2 & 0xFFFFFFC0u);

    float exact_v;
    {
#pragma clang fp contract(off)
        // Ambiguous: real runner-up within (rcp 2.4e-7 + 6-LSB-trunc 3.8e-6) margin.
        const bool ambig = (f2 > 0.0f) && ((f1 - f2) <= 1e-5f * f1);
        if (ambig) {
            // Exact-div argmax, first-max-wins — replicates numpy bit-for-bit.
            float bv = -1.0f; int nbi = 0;
            for (int m = 0; m < M_GT; ++m) {
                const float4 g = gt4[m];
                const float wx = fmaxf(fminf(g.z, p.z) - fmaxf(g.x, p.x), 0.0f);
                const float wy = fmaxf(fminf(g.w, p.w) - fmaxf(g.y, p.y), 0.0f);
                const float inter = wx * wy;
                const float iou = inter / ((ga_s[m] + ap) - inter);
                if (iou > bv) { bv = iou; nbi = m; }
            }
            bi = nbi;
        }
        // One exact IEEE div: matched_val of the winner (for the 0.5 test).
        const float4 g = gt4[bi];
        const float wx = fmaxf(fminf(g.z, p.z) - fmaxf(g.x, p.x), 0.0f);
        const float wy = fmaxf(fminf(g.w, p.w) - fmaxf(g.y, p.y), 0.0f);
        const float inter = wx * wy;
        exact_v = inter / ((ga_s[bi] + ap) - inter);
    }

    const int match = (exact_v < 0.5f) ? -1 : bi;  // FG==BG==0.5: BETWEEN dead

    const float4 mg = gt4[match < 0 ? 0 : match];
    const float aw = p.z - p.x;
    const float ah = p.w - p.y;
    const float ax = p.x + 0.5f * aw;
    const float ay = p.y + 0.5f * ah;
    const float gw = fmaxf(mg.z - mg.x, 1.0f);
    const float gh = fmaxf(mg.w - mg.y, 1.0f);
    const float gx = mg.x + 0.5f * gw;
    const float gy = mg.y + 0.5f * gh;

    float4 tgt;
    tgt.x = ((gx - ax) / aw) / 0.1f;
    tgt.y = ((gy - ay) / ah) / 0.1f;
    tgt.z = logf(gw / aw) / 0.2f;
    tgt.w = logf(gh / ah) / 0.2f;

    const float sx = d.x * 0.1f;
    const float sy = d.y * 0.1f;
    const float sw = d.z * 0.2f;
    const float sh = d.w * 0.2f;
    const float cx = ax + sx * aw;
    const float cy = ay + sy * ah;
    const float w2 = expf(sw) * aw;
    const float h2 = expf(sh) * ah;

    float4 dec;
    dec.x = cx - 0.5f * w2;
    dec.y = cy - 0.5f * h2;
    dec.z = cx + 0.5f * w2;
    dec.w = cy + 0.5f * h2;

    float4* pout4 = reinterpret_cast<float4*>(pout);
    const long BN = (long)B_IMGS * N_PROP;
    pout4[pi] = dec;
    pout4[BN + pi] = tgt;
    pout[2 * BN * 4 + pi] = (float)match;
}

// ---------- A/B: full 64-gt scan per thread (R9 structure) ----------
template<int REP>
__global__ __launch_bounds__(256) void roihead_full(
    const float* __restrict__ proposals, const float* __restrict__ gt,
    const float* __restrict__ deltas, float* __restrict__ out)
{
    __shared__ float ga_s[M_GT];

    const int b   = blockIdx.y;
    const int tid = threadIdx.x;
    {
        const float4* gs = reinterpret_cast<const float4*>(gt) + b * M_GT;
        if (tid < M_GT) {
            const float4 g = gs[tid];
            ga_s[tid] = (g.z - g.x) * (g.w - g.y);  // numpy op order
        }
    }
    __syncthreads();

    const int n = blockIdx.x * blockDim.x + tid;
    if (n >= N_PROP) return;

    for (int r = 0; r < REP; ++r) {
        const float* pprop = proposals;
        const float* pgt   = gt;
        const float* pdel  = deltas;
        float*       pout  = out;
        asm volatile("" : "+s"(pprop), "+s"(pgt), "+s"(pdel), "+s"(pout));

        const float4* __restrict__ gt4 =
            reinterpret_cast<const float4*>(pgt) + b * M_GT;
        const long pi = (long)b * N_PROP + n;
        const float4 p = reinterpret_cast<const float4*>(pprop)[pi];

        unsigned k1 = 0u, k2 = 0u;
        float ap;
        {
#pragma clang fp contract(off)
            ap = (p.z - p.x) * (p.w - p.y);
#pragma unroll 8
            for (int m = 0; m < M_GT; ++m) {
                const float4 g  = gt4[m];   // wave-uniform -> s_load
                const float  ga = ga_s[m];  // ds_read_b32
                const float wx = fmaxf(fminf(g.z, p.z) - fmaxf(g.x, p.x), 0.0f);
                const float wy = fmaxf(fminf(g.w, p.w) - fmaxf(g.y, p.y), 0.0f);
                const float inter = wx * wy;
                const float uni   = (ga + ap) - inter;
                const float a = inter * __builtin_amdgcn_rcpf(uni);
                const unsigned key =
                    (__float_as_uint(a) & 0xFFFFFFC0u) | (unsigned)(63 - m);
                const unsigned t = k1 < key ? k1 : key;
                k1 = k1 > key ? k1 : key;
                k2 = k2 > t   ? k2 : t;
            }
        }

        const float4 d = reinterpret_cast<const float4*>(pdel)[pi];
        finish_and_store(p, d, gt4, ga_s, ap, k1, k2, pout, pi);
    }
}

// ---------- C: m-split probe. Wave-pairs share 64 proposals; wave h scans
// gts [32h, 32h+32) (m wave-uniform -> s_load preserved); packed-key top-2
// merged via LDS; h0 wave runs the full epilogue with coalesced stores. ----
template<int REP>
__global__ __launch_bounds__(256) void roihead_split(
    const float* __restrict__ proposals, const float* __restrict__ gt,
    const float* __restrict__ deltas, float* __restrict__ out)
{
    __shared__ float ga_s[M_GT];
    __shared__ unsigned comb[2][64][2];  // [wave-pair][lane][k1,k2] from h1

    const int b    = blockIdx.y;
    const int tid  = threadIdx.x;
    const int wp   = tid >> 7;        // wave-pair within block (0/1)
    const int h    = (tid >> 6) & 1;  // which half of the gts (wave-uniform)
    const int lane = tid & 63;

    {
        const float4* gs = reinterpret_cast<const float4*>(gt) + b * M_GT;
        if (tid < M_GT) {
            const float4 g = gs[tid];
            ga_s[tid] = (g.z - g.x) * (g.w - g.y);
        }
    }
    __syncthreads();

    const int n = blockIdx.x * 128 + wp * 64 + lane;
    const bool valid = (n < N_PROP);
    const long pi = (long)b * N_PROP + (valid ? n : 0);  // clamped, loads safe

    for (int r = 0; r < REP; ++r) {
        const float* pprop = proposals;
        const float* pgt   = gt;
        const float* pdel  = deltas;
        float*       pout  = out;
        asm volatile("" : "+s"(pprop), "+s"(pgt), "+s"(pdel), "+s"(pout));

        const float4* __restrict__ gt4 =
            reinterpret_cast<const float4*>(pgt) + b * M_GT;
        const float4 p = reinterpret_cast<const float4*>(pprop)[pi];

        unsigned k1 = 0u, k2 = 0u;
        float ap;
        {
#pragma clang fp contract(off)
            ap = (p.z - p.x) * (p.w - p.y);
            const int mb = h * 32;       // wave-uniform
#pragma unroll 8
            for (int j = 0; j < 32; ++j) {
                const int m = mb + j;
                const float4 g  = gt4[m];   // wave-uniform -> s_load
                const float  ga = ga_s[m];
                const float wx = fmaxf(fminf(g.z, p.z) - fmaxf(g.x, p.x), 0.0f);
                const float wy = fmaxf(fminf(g.w, p.w) - fmaxf(g.y, p.y), 0.0f);
                const float inter = wx * wy;
                const float uni   = (ga + ap) - inter;
                const float a = inter * __builtin_amdgcn_rcpf(uni);
                const unsigned key =
                    (__float_as_uint(a) & 0xFFFFFFC0u) | (unsigned)(63 - m);
                const unsigned t = k1 < key ? k1 : key;
                k1 = k1 > key ? k1 : key;
                k2 = k2 > t   ? k2 : t;
            }
        }

        if (h == 1) { comb[wp][lane][0] = k1; comb[wp][lane][1] = k2; }
        __syncthreads();
        if (h == 0) {                       // wave-uniform branch, no divergence
            const unsigned ok1 = comb[wp][lane][0];
            const unsigned ok2 = comb[wp][lane][1];
            const unsigned lo = k1 < ok1 ? k1 : ok1;
            k1 = k1 > ok1 ? k1 : ok1;
            k2 = k2 > ok2 ? k2 : ok2;
            k2 = k2 > lo  ? k2 : lo;
            if (valid) {
                const float4 d = reinterpret_cast<const float4*>(pdel)[pi];
                finish_and_store(p, d, gt4, ga_s, ap, k1, k2, pout, pi);
            }
        }
        __syncthreads();  // protect comb against next rep's overwrite
    }
}

extern "C" void kernel_launch(void* const* d_in, const int* in_sizes, int n_in,
                              void* d_out, int out_size, void* d_ws, size_t ws_size,
                              hipStream_t stream) {
    const float* proposals = (const float*)d_in[0];
    const float* gt        = (const float*)d_in[1];
    const float* deltas    = (const float*)d_in[2];
    float* out = (float*)d_out;

    dim3 block(256);
    dim3 gridA((N_PROP + 255) / 256, B_IMGS);   // full-scan: 1 prop/thread
    dim3 gridC((N_PROP + 127) / 128, B_IMGS);   // split: 128 props/block

    // A: anchor (REP=1, R9-identical math)
    roihead_full<1><<<gridA, block, 0, stream>>>(proposals, gt, deltas, out);
    // C: occupancy probe (REP=4) — timing only; overwritten by B below
    roihead_split<4><<<gridC, block, 0, stream>>>(proposals, gt, deltas, out);
    // B: counter-surfacing run (REP=3), bit-identical math to A, writes last
    roihead_full<3><<<gridA, block, 0, stream>>>(proposals, gt, deltas, out);
}

// Round 12
// 156.967 us; speedup vs baseline: 1.4522x; 1.4522x over previous
//
#include <hip/hip_runtime.h>

// Problem constants (from setup_inputs): B=4, N=100000, M=64
#define B_IMGS 4
#define N_PROP 100000
#define HALF   50000          // V=2: each thread handles proposals n and n+HALF
#define M_GT   64

// Output layout (flat f32): decoded[B*N*4] | targets[B*N*4] | matches[B*N]
//
// R12 = R11 with the pragma placement fixed (compile error: '#pragma clang fp'
// must open a compound statement). Design unchanged:
// prologue packs ws[B][64][8] = {x1,y1,x2,y2,area,_,_,_} (32B stride); hot
// loop reads boxes+areas ONLY via wave-uniform s_load (scalar cache) ->
// unroll-8 chunk needs one lgkm wait, then pure VALU. No LDS in hot kernel.
// V=2 proposals/lane amortizes overheads and doubles ILP. Packed-key top-2
// argmax (v_min/max_u32) + 1e-5-margin exact-div fallback unchanged from R9.
// REP=3 probe (bit-identical, writes last) surfaces counters.

// ---------- prologue: pack {box, area} for SMEM streaming ----------
__global__ void prep_kernel(const float* __restrict__ gt, float* __restrict__ ws)
{
    const int t = threadIdx.x;              // t = b*64 + m, 256 threads exactly
    {
#pragma clang fp contract(off)
        const float4 g = reinterpret_cast<const float4*>(gt)[t];
        const float ga = (g.z - g.x) * (g.w - g.y);   // numpy op order
        reinterpret_cast<float4*>(ws)[t * 2] = g;
        ws[t * 8 + 4] = ga;
    }
}

// ---------- epilogue: fallback + threshold + encode + decode ----------
__device__ __forceinline__ void finish_and_store(
    const float4 p, const float4 d, const float4* __restrict__ gt4,
    float ap, unsigned k1, unsigned k2, float* __restrict__ pout, long pi)
{
    int bi = 63 - (int)(k1 & 63u);
    const float f1 = __uint_as_float(k1 & 0xFFFFFFC0u);
    const float f2 = __uint_as_float(k2 & 0xFFFFFFC0u);

    float exact_v;
    {
#pragma clang fp contract(off)
        // Ambiguous: real runner-up within (rcp 2.4e-7 + 6-LSB-trunc 3.8e-6) margin.
        const bool ambig = (f2 > 0.0f) && ((f1 - f2) <= 1e-5f * f1);
        if (ambig) {
            // Exact-div argmax, first-max-wins — replicates numpy bit-for-bit.
            float bv = -1.0f; int nbi = 0;
            for (int m = 0; m < M_GT; ++m) {
                const float4 g = gt4[m];
                const float ga = (g.z - g.x) * (g.w - g.y);  // numpy op order
                const float wx = fmaxf(fminf(g.z, p.z) - fmaxf(g.x, p.x), 0.0f);
                const float wy = fmaxf(fminf(g.w, p.w) - fmaxf(g.y, p.y), 0.0f);
                const float inter = wx * wy;
                const float iou = inter / ((ga + ap) - inter);
                if (iou > bv) { bv = iou; nbi = m; }
            }
            bi = nbi;
        }
        // One exact IEEE div: matched_val of the winner (for the 0.5 test).
        const float4 g = gt4[bi];
        const float ga = (g.z - g.x) * (g.w - g.y);
        const float wx = fmaxf(fminf(g.z, p.z) - fmaxf(g.x, p.x), 0.0f);
        const float wy = fmaxf(fminf(g.w, p.w) - fmaxf(g.y, p.y), 0.0f);
        const float inter = wx * wy;
        exact_v = inter / ((ga + ap) - inter);
    }

    const int match = (exact_v < 0.5f) ? -1 : bi;  // FG==BG==0.5: BETWEEN dead

    const float4 mg = gt4[match < 0 ? 0 : match];
    const float aw = p.z - p.x;
    const float ah = p.w - p.y;
    const float ax = p.x + 0.5f * aw;
    const float ay = p.y + 0.5f * ah;
    const float gw = fmaxf(mg.z - mg.x, 1.0f);
    const float gh = fmaxf(mg.w - mg.y, 1.0f);
    const float gx = mg.x + 0.5f * gw;
    const float gy = mg.y + 0.5f * gh;

    float4 tgt;
    tgt.x = ((gx - ax) / aw) / 0.1f;
    tgt.y = ((gy - ay) / ah) / 0.1f;
    tgt.z = logf(gw / aw) / 0.2f;
    tgt.w = logf(gh / ah) / 0.2f;

    const float sx = d.x * 0.1f;
    const float sy = d.y * 0.1f;
    const float sw = d.z * 0.2f;
    const float sh = d.w * 0.2f;
    const float cx = ax + sx * aw;
    const float cy = ay + sy * ah;
    const float w2 = expf(sw) * aw;
    const float h2 = expf(sh) * ah;

    float4 dec;
    dec.x = cx - 0.5f * w2;
    dec.y = cy - 0.5f * h2;
    dec.z = cx + 0.5f * w2;
    dec.w = cy + 0.5f * h2;

    float4* pout4 = reinterpret_cast<float4*>(pout);
    const long BN = (long)B_IMGS * N_PROP;
    pout4[pi] = dec;
    pout4[BN + pi] = tgt;
    pout[2 * BN * 4 + pi] = (float)match;
}

// ---------- hot kernel: SMEM-only loop data, V=2 proposals/lane ----------
template<int REP>
__global__ __launch_bounds__(256) void roihead_kernel(
    const float* __restrict__ proposals, const float* __restrict__ gt,
    const float* __restrict__ deltas, const float* __restrict__ wsin,
    float* __restrict__ out)
{
    const int b = blockIdx.y;
    const int n = blockIdx.x * blockDim.x + threadIdx.x;
    if (n >= HALF) return;

    for (int r = 0; r < REP; ++r) {
        const float* pprop = proposals;
        const float* pgt   = gt;
        const float* pdel  = deltas;
        const float* pws   = wsin;
        float*       pout  = out;
        asm volatile("" : "+s"(pprop), "+s"(pgt), "+s"(pdel), "+s"(pws), "+s"(pout));

        const float4* __restrict__ w4 =
            reinterpret_cast<const float4*>(pws) + b * (M_GT * 2);
        const float4* __restrict__ gt4 =
            reinterpret_cast<const float4*>(pgt) + b * M_GT;

        const long pi0 = (long)b * N_PROP + n;
        const long pi1 = pi0 + HALF;
        const float4 p0 = reinterpret_cast<const float4*>(pprop)[pi0];
        const float4 p1 = reinterpret_cast<const float4*>(pprop)[pi1];

        unsigned k1a = 0u, k2a = 0u, k1b = 0u, k2b = 0u;
        float ap0, ap1;
        {
#pragma clang fp contract(off)
            ap0 = (p0.z - p0.x) * (p0.w - p0.y);
            ap1 = (p1.z - p1.x) * (p1.w - p1.y);
#pragma unroll 8
            for (int m = 0; m < M_GT; ++m) {
                const float4 g  = w4[2 * m];        // wave-uniform -> s_load
                const float  ga = w4[2 * m + 1].x;  // s_load_dword (packed area)
                {
                    const float wx = fmaxf(fminf(g.z, p0.z) - fmaxf(g.x, p0.x), 0.0f);
                    const float wy = fmaxf(fminf(g.w, p0.w) - fmaxf(g.y, p0.y), 0.0f);
                    const float inter = wx * wy;
                    const float uni   = (ga + ap0) - inter;
                    const float a = inter * __builtin_amdgcn_rcpf(uni);
                    const unsigned key =
                        (__float_as_uint(a) & 0xFFFFFFC0u) | (unsigned)(63 - m);
                    const unsigned t = k1a < key ? k1a : key;
                    k1a = k1a > key ? k1a : key;
                    k2a = k2a > t   ? k2a : t;
                }
                {
                    const float wx = fmaxf(fminf(g.z, p1.z) - fmaxf(g.x, p1.x), 0.0f);
                    const float wy = fmaxf(fminf(g.w, p1.w) - fmaxf(g.y, p1.y), 0.0f);
                    const float inter = wx * wy;
                    const float uni   = (ga + ap1) - inter;
                    const float a = inter * __builtin_amdgcn_rcpf(uni);
                    const unsigned key =
                        (__float_as_uint(a) & 0xFFFFFFC0u) | (unsigned)(63 - m);
                    const unsigned t = k1b < key ? k1b : key;
                    k1b = k1b > key ? k1b : key;
                    k2b = k2b > t   ? k2b : t;
                }
            }
        }

        const float4 d0 = reinterpret_cast<const float4*>(pdel)[pi0];
        const float4 d1 = reinterpret_cast<const float4*>(pdel)[pi1];
        finish_and_store(p0, d0, gt4, ap0, k1a, k2a, pout, pi0);
        finish_and_store(p1, d1, gt4, ap1, k1b, k2b, pout, pi1);
    }
}

extern "C" void kernel_launch(void* const* d_in, const int* in_sizes, int n_in,
                              void* d_out, int out_size, void* d_ws, size_t ws_size,
                              hipStream_t stream) {
    const float* proposals = (const float*)d_in[0];
    const float* gt        = (const float*)d_in[1];
    const float* deltas    = (const float*)d_in[2];
    float* out = (float*)d_out;
    float* ws  = (float*)d_ws;   // needs 4*64*8*4 = 8 KB

    // Prologue: pack {box, area} (ws is re-poisoned before every call).
    prep_kernel<<<1, 256, 0, stream>>>(gt, ws);

    dim3 block(256);
    dim3 grid((HALF + 255) / 256, B_IMGS);
    // A: the real kernel (REP=1)
    roihead_kernel<1><<<grid, block, 0, stream>>>(proposals, gt, deltas, ws, out);
    // B: counter probe (REP=3), bit-identical math, writes last
    roihead_kernel<3><<<grid, block, 0, stream>>>(proposals, gt, deltas, ws, out);
}